// Round 1
// baseline (1017.986 us; speedup 1.0000x reference)
//
#include <hip/hip_runtime.h>

#define B_ 4
#define S_ 4096
#define D_ 1024
#define H_ 16
#define DH 64
#define CHUNK 64
#define NC (S_ / CHUNK)   // 64 chunks
#define BH (B_ * H_)      // 64 (b,h) sequences
#define STATE_N 4160      // 64*64 S entries + 64 z entries
#define EPS 1e-6f

typedef __bf16 bf16;
typedef __bf16 bf16x8 __attribute__((ext_vector_type(8)));
typedef __bf16 bf16x4 __attribute__((ext_vector_type(4)));
typedef float v4f __attribute__((ext_vector_type(4)));

#define MFMA16(a, b, c) __builtin_amdgcn_mfma_f32_16x16x32_bf16(a, b, c, 0, 0, 0)

// async global->LDS, 16B per lane; LDS dest = wave-uniform base + lane*16
__device__ __forceinline__ void load_lds16(const bf16* g, bf16* l) {
  __builtin_amdgcn_global_load_lds(
      (const __attribute__((address_space(1))) unsigned int*)g,
      (__attribute__((address_space(3))) unsigned int*)l, 16, 0, 0);
}

// ---------------------------------------------------------------------------
// fp32 -> bf16 convert (x): 8 elems/thread, vectorized.
// ---------------------------------------------------------------------------
__global__ __launch_bounds__(256) void cvt_f32_bf16(const float* __restrict__ in,
                                                    bf16* __restrict__ out) {
  const size_t i = ((size_t)blockIdx.x * 256 + threadIdx.x) * 8;
  float4 a = *(const float4*)(in + i);
  float4 b = *(const float4*)(in + i + 4);
  bf16x8 o;
  o[0] = (bf16)a.x; o[1] = (bf16)a.y; o[2] = (bf16)a.z; o[3] = (bf16)a.w;
  o[4] = (bf16)b.x; o[5] = (bf16)b.y; o[6] = (bf16)b.z; o[7] = (bf16)b.w;
  *(bf16x8*)(out + i) = o;
}

// ---------------------------------------------------------------------------
// Fused weight transpose + fp32->bf16 for all 4 weights (z selects matrix).
// ---------------------------------------------------------------------------
__global__ __launch_bounds__(256) void transpose_w4(
    const float* __restrict__ w0, const float* __restrict__ w1,
    const float* __restrict__ w2, const float* __restrict__ w3,
    bf16* __restrict__ out) {
  __shared__ float tile[32][33];
  const int z = blockIdx.z;
  const float* in = (z == 0) ? w0 : (z == 1) ? w1 : (z == 2) ? w2 : w3;
  bf16* o = out + (size_t)z * D_ * D_;
  const int bx = blockIdx.x * 32, by = blockIdx.y * 32;
  const int tx = threadIdx.x & 31, ty = threadIdx.x >> 5;  // 32 x 8
#pragma unroll
  for (int i = 0; i < 32; i += 8)
    tile[ty + i][tx] = in[(size_t)(by + ty + i) * D_ + bx + tx];
  __syncthreads();
#pragma unroll
  for (int i = 0; i < 32; i += 8)
    o[(size_t)(bx + ty + i) * D_ + by + tx] = (bf16)tile[tx][ty + i];
}

// ---------------------------------------------------------------------------
// 256x256 8-phase NT GEMM (m201-style schedule in plain HIP).
// BK=64, 8 waves (2M x 4N), LDS 128KB double-buffered, global_load_lds x16B.
// Wave quadrant interleave: wave wr owns rows wr*64 + mh*128 + m*16+...,
// wave wc owns cols wc*32 + nh*128 + n*16+... -> phase (mh,nh) consumes
// exactly staged A-half mh and B-half nh.
// LDS layout per matrix: [dbuf s][half h][ks][128 rows][32 cols] bf16.
// Swizzle (involution): LDS slot (r, g) holds global group g ^ ((r>>2)&3);
// read uses q' = quad ^ ((l16>>2)&3)  -> 2-way bank aliasing only (free).
// Counted vmcnt: steady 4/4/-/4 per tile, epilogue drains 2 -> 0.
// ---------------------------------------------------------------------------
#define PHASE(S, MH, NH, LA, LB, STMT, WN)                                     \
  do {                                                                         \
    if (LA) {                                                                  \
      _Pragma("unroll") for (int m = 0; m < 4; m++) {                          \
        aR[m][0] = *(const bf16x8*)&lds[(S)*16384 + (MH)*8192 + m*512 + aoff]; \
        aR[m][1] = *(const bf16x8*)&lds[(S)*16384 + (MH)*8192 + 4096 + m*512 + aoff]; \
      }                                                                        \
    }                                                                          \
    if (LB) {                                                                  \
      _Pragma("unroll") for (int n = 0; n < 2; n++) {                          \
        bR[NH][n][0] = *(const bf16x8*)&lds[(S)*16384 + (NH)*8192 + n*512 + boff]; \
        bR[NH][n][1] = *(const bf16x8*)&lds[(S)*16384 + (NH)*8192 + 4096 + n*512 + boff]; \
      }                                                                        \
    }                                                                          \
    STMT;                                                                      \
    if ((WN) == 4) asm volatile("s_waitcnt vmcnt(4)" ::: "memory");            \
    else if ((WN) == 2) asm volatile("s_waitcnt vmcnt(2)" ::: "memory");       \
    else if ((WN) == 0) asm volatile("s_waitcnt vmcnt(0)" ::: "memory");       \
    __builtin_amdgcn_s_barrier();                                              \
    __builtin_amdgcn_s_setprio(1);                                             \
    _Pragma("unroll") for (int ks = 0; ks < 2; ks++)                           \
      _Pragma("unroll") for (int m = 0; m < 4; m++)                            \
        _Pragma("unroll") for (int n = 0; n < 2; n++)                          \
          acc[MH][m][NH][n] = MFMA16(aR[m][ks], bR[NH][n][ks], acc[MH][m][NH][n]); \
    __builtin_amdgcn_s_setprio(0);                                             \
    __builtin_amdgcn_s_barrier();                                              \
  } while (0)

__global__ __launch_bounds__(512, 2) void gemm256(const bf16* __restrict__ A,
                                                  const bf16* __restrict__ BT,
                                                  bf16* __restrict__ o0,
                                                  bf16* __restrict__ o1,
                                                  bf16* __restrict__ o2,
                                                  float* __restrict__ of) {
  __shared__ __align__(16) bf16 lds[65536];  // A at 0 (64KB), B at 32768 (64KB)
  const int tid = threadIdx.x;
  const int wv = tid >> 6, lane = tid & 63;
  const int quad = lane >> 4, l16 = lane & 15;
  const int wr = wv >> 2, wc = wv & 3;  // 2 x 4 wave grid
  const int bm = blockIdx.x * 256;
  const int by = blockIdx.y;
  const int zz = of ? 0 : (by >> 2);
  const int colg = of ? by * 256 : (by & 3) * 256;
  const int act = (of == nullptr) && (zz < 2);
  bf16* ob = (zz == 0) ? o0 : (zz == 1) ? o1 : o2;

  // ---- staging source pointers (per-lane, inverse-swizzled group) ----
  const int r = tid >> 2;                      // 0..127: row within half
  const int gsw = (tid & 3) ^ ((r >> 2) & 3);  // swizzled 8-elem group
  const bf16* sA0 = A + (size_t)(bm + r) * D_ + gsw * 8;
  const bf16* sA1 = A + (size_t)(bm + 128 + r) * D_ + gsw * 8;
  const bf16* sB0 = BT + ((size_t)by * 256 + r) * D_ + gsw * 8;
  const bf16* sB1 = BT + ((size_t)by * 256 + 128 + r) * D_ + gsw * 8;

  auto stageA = [&](int h, int kt, int s) {
    const bf16* src = (h ? sA1 : sA0) + kt * 64;
    bf16* d = &lds[s * 16384 + h * 8192 + wv * 512];  // wave-uniform base
    load_lds16(src, d);           // ks0
    load_lds16(src + 32, d + 4096);  // ks1
  };
  auto stageB = [&](int h, int kt, int s) {
    const bf16* src = (h ? sB1 : sB0) + kt * 64;
    bf16* d = &lds[32768 + s * 16384 + h * 8192 + wv * 512];
    load_lds16(src, d);
    load_lds16(src + 32, d + 4096);
  };

  // ---- read-side offsets (elements), swizzled ----
  const int qsw = quad ^ ((l16 >> 2) & 3);
  const int aoff = (wr * 64 + l16) * 32 + qsw * 8;
  const int boff = 32768 + (wc * 32 + l16) * 32 + qsw * 8;

  v4f acc[2][4][2][2];
#pragma unroll
  for (int a0 = 0; a0 < 2; a0++)
#pragma unroll
    for (int a1 = 0; a1 < 4; a1++)
#pragma unroll
      for (int a2 = 0; a2 < 2; a2++)
#pragma unroll
        for (int a3 = 0; a3 < 2; a3++) acc[a0][a1][a2][a3] = (v4f){0.f, 0.f, 0.f, 0.f};
  bf16x8 aR[4][2];
  bf16x8 bR[2][2][2];

  // ---- prologue: stage tile 0 into s=0, issue order A0,B0,B1,A1 ----
  stageA(0, 0, 0); stageB(0, 0, 0); stageB(1, 0, 0); stageA(1, 0, 0);
  asm volatile("s_waitcnt vmcnt(4)" ::: "memory");  // A0,B0 landed
  __builtin_amdgcn_s_barrier();

  constexpr int NK = D_ / 64;  // 16 K-tiles
#pragma unroll 1
  for (int t = 0; t < NK; t += 2) {
    // tile t (s=0): stage t+1 -> s=1  (t+1 <= 15 always)
    PHASE(0, 0, 0, 1, 1, stageA(0, t + 1, 1), 4);
    PHASE(0, 0, 1, 0, 1, stageB(0, t + 1, 1), 4);
    PHASE(0, 1, 1, 1, 0, stageB(1, t + 1, 1), -1);
    PHASE(0, 1, 0, 0, 0, stageA(1, t + 1, 1), 4);
    if (t + 2 < NK) {
      // tile t+1 (s=1): stage t+2 -> s=0
      PHASE(1, 0, 0, 1, 1, stageA(0, t + 2, 0), 4);
      PHASE(1, 0, 1, 0, 1, stageB(0, t + 2, 0), 4);
      PHASE(1, 1, 1, 1, 0, stageB(1, t + 2, 0), -1);
      PHASE(1, 1, 0, 0, 0, stageA(1, t + 2, 0), 4);
    } else {
      // last tile: epilogue drain 2 -> 0
      PHASE(1, 0, 0, 1, 1, (void)0, 2);
      PHASE(1, 0, 1, 0, 1, (void)0, 0);
      PHASE(1, 1, 1, 1, 0, (void)0, -1);
      PHASE(1, 1, 0, 0, 0, (void)0, -1);
    }
  }

  // ---- coalesced epilogue through LDS (reuse), stride 260 f32 ----
  __syncthreads();
  float* Cl = (float*)lds;  // [2 wr][32 rows][260]
  const int erow = tid >> 3;            // 0..63
  const int wrr = erow >> 5, mrow = erow & 31;
  const int seg = (tid & 7) * 32;       // f32 segment
#pragma unroll
  for (int i = 0; i < 4; i++) {
    const int mh = i >> 1, mp = i & 1;
#pragma unroll
    for (int mm = 0; mm < 2; mm++) {
      const int m = mp * 2 + mm;
#pragma unroll
      for (int nh = 0; nh < 2; nh++)
#pragma unroll
        for (int n = 0; n < 2; n++)
#pragma unroll
          for (int rr = 0; rr < 4; rr++) {
            float x = acc[mh][m][nh][n][rr];
            if (act) x = x > 0.f ? x + 1.f : __expf(x);
            Cl[(wr * 32 + mm * 16 + quad * 4 + rr) * 260 +
               nh * 128 + wc * 32 + n * 16 + l16] = x;
          }
    }
    __syncthreads();
    const float* srcp = &Cl[(wrr * 32 + mrow) * 260 + seg];
    const size_t grow = (size_t)(bm + mh * 128 + wrr * 64 + mp * 32 + mrow);
    if (of) {
      float* dst = of + grow * D_ + colg + seg;
#pragma unroll
      for (int u = 0; u < 8; u++)
        *(float4*)(dst + u * 4) = *(const float4*)(srcp + u * 4);
    } else {
      bf16* dst = ob + grow * D_ + colg + seg;
#pragma unroll
      for (int u = 0; u < 4; u++) {
        bf16x8 q;
#pragma unroll
        for (int e = 0; e < 8; e++) q[e] = (bf16)srcp[u * 8 + e];
        *(bf16x8*)(dst + u * 8) = q;
      }
    }
    __syncthreads();
  }
}

// ---------------------------------------------------------------------------
// Pass 1: per-chunk KV outer-product sums + k-sums (fp32).
// ---------------------------------------------------------------------------
__global__ __launch_bounds__(256) void chunk_kv(const bf16* __restrict__ kb,
                                                const bf16* __restrict__ vb,
                                                float* __restrict__ states) {
  constexpr int LD = 88;
  __shared__ bf16 Kl[CHUNK * LD];
  __shared__ bf16 Vl[CHUNK * LD];
  const int tid = threadIdx.x;
  const int c = blockIdx.x, bh = blockIdx.y;
  const int b = bh >> 4, h = bh & 15;
  const size_t gbase = ((size_t)(b * S_ + c * CHUNK)) * D_ + h * DH;
#pragma unroll
  for (int rep = 0; rep < 2; rep++) {
    int flat = tid + rep * 256;
    int rr = flat >> 3, sg = (flat & 7) * 8;
    *(bf16x8*)&Kl[rr * LD + sg] = *(const bf16x8*)(kb + gbase + (size_t)rr * D_ + sg);
    *(bf16x8*)&Vl[rr * LD + sg] = *(const bf16x8*)(vb + gbase + (size_t)rr * D_ + sg);
  }
  __syncthreads();
  const int d0 = (tid >> 4) * 4, e0 = (tid & 15) * 4;
  float acc[4][4] = {};
  for (int t = 0; t < CHUNK; t++) {
    bf16x4 k4 = *(const bf16x4*)&Kl[t * LD + d0];
    bf16x4 v4 = *(const bf16x4*)&Vl[t * LD + e0];
    float kf[4], vf[4];
#pragma unroll
    for (int i = 0; i < 4; i++) { kf[i] = (float)k4[i]; vf[i] = (float)v4[i]; }
#pragma unroll
    for (int i = 0; i < 4; i++)
#pragma unroll
      for (int j = 0; j < 4; j++) acc[i][j] += kf[i] * vf[j];
  }
  float* out = states + ((size_t)bh * NC + c) * STATE_N;
#pragma unroll
  for (int i = 0; i < 4; i++)
#pragma unroll
    for (int j = 0; j < 4; j++) out[(d0 + i) * 64 + (e0 + j)] = acc[i][j];
  if (tid < 64) {
    float zs = 0.f;
    for (int t = 0; t < CHUNK; t++) zs += (float)Kl[t * LD + tid];
    out[4096 + tid] = zs;
  }
}

// ---------------------------------------------------------------------------
// Exclusive prefix over chunks + state_cache init (fp32 input).
// ---------------------------------------------------------------------------
__global__ __launch_bounds__(256) void state_prefix(const float* __restrict__ sc,
                                                    float* __restrict__ states) {
  const int bh = blockIdx.x;
  const int e = blockIdx.y * 256 + threadIdx.x;
  if (e >= STATE_N) return;
  const float* scb = sc + (size_t)bh * (DH + 1) * DH;
  float run = scb[e];
  float* p = states + (size_t)bh * NC * STATE_N + e;
  for (int c = 0; c < NC; c++) {
    float tmp = p[(size_t)c * STATE_N];
    p[(size_t)c * STATE_N] = run;
    run += tmp;
  }
}

// ---------------------------------------------------------------------------
// Pass 2: P = mask(Q K^T), num = P@V + Q@S0, den = rowsum(P) + Q.z0.
// ---------------------------------------------------------------------------
__global__ __launch_bounds__(256) void attn_pass2(
    const bf16* __restrict__ qb, const bf16* __restrict__ kb,
    const bf16* __restrict__ vb, const float* __restrict__ states,
    bf16* __restrict__ ao) {
  constexpr int LD = 88;
  __shared__ bf16 Ql[CHUNK * LD];
  __shared__ bf16 Kl[CHUNK * LD];
  __shared__ bf16 VT[DH * LD];
  __shared__ bf16 S0T[DH * LD];
  __shared__ bf16 Pl[CHUNK * LD];
  __shared__ float denl[CHUNK];
  __shared__ float z0l[DH];
  const int tid = threadIdx.x;
  const int wave = tid >> 6, lane = tid & 63;
  const int quad = lane >> 4, l16 = lane & 15;
  const int c = blockIdx.x, bh = blockIdx.y;
  const int b = bh >> 4, h = bh & 15;
  const size_t gbase = ((size_t)(b * S_ + c * CHUNK)) * D_ + h * DH;

#pragma unroll
  for (int rep = 0; rep < 2; rep++) {
    int flat = tid + rep * 256;
    int rr = flat >> 3, sg = (flat & 7) * 8;
    *(bf16x8*)&Ql[rr * LD + sg] = *(const bf16x8*)(qb + gbase + (size_t)rr * D_ + sg);
    *(bf16x8*)&Kl[rr * LD + sg] = *(const bf16x8*)(kb + gbase + (size_t)rr * D_ + sg);
    bf16x8 vv = *(const bf16x8*)(vb + gbase + (size_t)rr * D_ + sg);
#pragma unroll
    for (int u = 0; u < 8; u++) VT[(sg + u) * LD + rr] = vv[u];
  }
  const float* st = states + ((size_t)bh * NC + c) * STATE_N;
  for (int f = tid; f < 4096; f += 256) S0T[(f & 63) * LD + (f >> 6)] = (bf16)st[f];
  if (tid < DH) z0l[tid] = st[4096 + tid];
  __syncthreads();

  v4f zero = {0.f, 0.f, 0.f, 0.f};
  v4f pacc[4];
#pragma unroll
  for (int j = 0; j < 4; j++) pacc[j] = zero;
#pragma unroll
  for (int ks = 0; ks < 2; ks++) {
    bf16x8 aq = *(const bf16x8*)&Ql[(wave * 16 + l16) * LD + ks * 32 + quad * 8];
#pragma unroll
    for (int j = 0; j < 4; j++) {
      bf16x8 bk = *(const bf16x8*)&Kl[(j * 16 + l16) * LD + ks * 32 + quad * 8];
      pacc[j] = MFMA16(aq, bk, pacc[j]);
    }
  }
  float rs[4] = {0.f, 0.f, 0.f, 0.f};
#pragma unroll
  for (int j = 0; j < 4; j++) {
#pragma unroll
    for (int rr = 0; rr < 4; rr++) {
      int t = wave * 16 + quad * 4 + rr;
      int col = j * 16 + l16;
      float p = (col <= t) ? pacc[j][rr] : 0.f;
      Pl[t * LD + col] = (bf16)p;
      rs[rr] += p;
    }
  }
#pragma unroll
  for (int m = 1; m < 16; m <<= 1)
#pragma unroll
    for (int rr = 0; rr < 4; rr++) rs[rr] += __shfl_xor(rs[rr], m, 64);
  if (l16 == 0)
#pragma unroll
    for (int rr = 0; rr < 4; rr++) denl[wave * 16 + quad * 4 + rr] = rs[rr];
  __syncthreads();
  if (tid < CHUNK) {
    float qz = 0.f;
    for (int d = 0; d < DH; d++) qz += (float)Ql[tid * LD + d] * z0l[d];
    denl[tid] += qz;
  }
  __syncthreads();

  v4f nacc[4];
#pragma unroll
  for (int j = 0; j < 4; j++) nacc[j] = zero;
#pragma unroll
  for (int ks = 0; ks < 2; ks++) {
    bf16x8 ap = *(const bf16x8*)&Pl[(wave * 16 + l16) * LD + ks * 32 + quad * 8];
#pragma unroll
    for (int j = 0; j < 4; j++) {
      bf16x8 bv = *(const bf16x8*)&VT[(j * 16 + l16) * LD + ks * 32 + quad * 8];
      nacc[j] = MFMA16(ap, bv, nacc[j]);
    }
  }
#pragma unroll
  for (int ks = 0; ks < 2; ks++) {
    bf16x8 aq = *(const bf16x8*)&Ql[(wave * 16 + l16) * LD + ks * 32 + quad * 8];
#pragma unroll
    for (int j = 0; j < 4; j++) {
      bf16x8 bs = *(const bf16x8*)&S0T[(j * 16 + l16) * LD + ks * 32 + quad * 8];
      nacc[j] = MFMA16(aq, bs, nacc[j]);
    }
  }
#pragma unroll
  for (int j = 0; j < 4; j++) {
#pragma unroll
    for (int rr = 0; rr < 4; rr++) {
      int t = wave * 16 + quad * 4 + rr;
      int e = j * 16 + l16;
      float o = nacc[j][rr] / (denl[t] + EPS);
      ao[gbase + (size_t)t * D_ + e] = (bf16)o;
    }
  }
}

// ---------------------------------------------------------------------------
extern "C" void kernel_launch(void* const* d_in, const int* in_sizes, int n_in,
                              void* d_out, int out_size, void* d_ws, size_t ws_size,
                              hipStream_t stream) {
  const float* x  = (const float*)d_in[0];
  const float* sc = (const float*)d_in[1];
  const float* Wq = (const float*)d_in[2];
  const float* Wk = (const float*)d_in[3];
  const float* Wv = (const float*)d_in[4];
  const float* Wo = (const float*)d_in[5];
  float* out = (float*)d_out;

  const size_t MSZ = (size_t)B_ * S_ * D_;  // 16,777,216 elems
  const size_t WSZ = (size_t)D_ * D_;       // 1,048,576 elems
  bf16* xb = (bf16*)d_ws;
  bf16* qb = xb + MSZ;
  bf16* kb = qb + MSZ;
  bf16* vb = kb + MSZ;
  bf16* ao = vb + MSZ;
  bf16* wt = ao + MSZ;  // 4 transposed bf16 weight matrices [q|k|v|o]
  float* states = (float*)(wt + 4 * WSZ);  // BH*NC*4160 fp32 (~68 MB)

  cvt_f32_bf16<<<MSZ / (256 * 8), 256, 0, stream>>>(x, xb);
  transpose_w4<<<dim3(32, 32, 4), 256, 0, stream>>>(Wq, Wk, Wv, Wo, wt);

  // fused QKV GEMM: BT rows 0..3071 span wt[q|k|v]; 256x256 tiles
  gemm256<<<dim3(64, 12), 512, 0, stream>>>(xb, wt, qb, kb, vb, nullptr);

  chunk_kv<<<dim3(NC, BH), 256, 0, stream>>>(kb, vb, states);
  state_prefix<<<dim3(BH, 17), 256, 0, stream>>>(sc, states);
  attn_pass2<<<dim3(NC, BH), 256, 0, stream>>>(qb, kb, vb, states, ao);

  gemm256<<<dim3(64, 4), 512, 0, stream>>>(ao, wt + 3 * WSZ, nullptr, nullptr,
                                           nullptr, out);
}